// Round 1
// baseline (134.732 us; speedup 1.0000x reference)
//
#include <hip/hip_runtime.h>
#include <math.h>

#define NN 4096
#define DD 512
#define MARGINF 1.0f
#define NCLS 64
#define MAXM 160
#define TRI (MAXM * (MAXM - 1) / 2)    // 12720
#define PBLK 32                         // 128-row panels
#define NBLK2 (PBLK * (PBLK + 1) / 2)   // 528 triangular 128x128 tiles
#define NSLICE 4                        // pair2 blocks per class

typedef __attribute__((ext_vector_type(8))) short bf16x8;  // 8 bf16 (4 VGPRs)
typedef __attribute__((ext_vector_type(4))) float f32x4;   // 4 fp32 acc

// ws layout (float indices):
#define WS_SQ   0         // float[4096] ||x_i||^2
#define WS_NS   4096      // float[4096] neg_sum
#define WS_LOSS 8192      // float[1] sum hinge^2
#define WS_CTR  8193      // uint[1] pair2 completion counter
#define WS_LENP 8194      // float[1] sum over classes mc*(mc-1)
#define WS_RK   8320      // int[4096] rank within class (atomic-free)
#define WS_MEM  12416     // int[64*160] class member lists (rank-indexed)
#define WS_XF   32768     // ushort[4096*512] FRAGMENT-MAJOR bf16 X (4 MB)
                          //   frag(r16,kb) = 1KB at short-off (r16*16+kb)*512;
                          //   element (q*16+m)*8+e  (lane=q*16+m, e=k&7)
#define WS_PD   1081344   // float[64*TRI] positive-pair distances

__device__ __forceinline__ unsigned short f2bf(float f) {
    unsigned u = __float_as_uint(f);
    u += 0x7fffu + ((u >> 16) & 1u);   // round-to-nearest-even
    return (unsigned short)(u >> 16);
}

// Row norms + fragment-major bf16 conversion + ATOMIC-FREE class ranks.
__global__ __launch_bounds__(256) void prep_kernel(const float* __restrict__ X,
                                                   const int* __restrict__ tgt,
                                                   float* __restrict__ ws) {
    __shared__ int tg[NN];   // 16 KB
    const int tid = threadIdx.x;
    for (int j = tid; j < NN; j += 256) tg[j] = tgt[j];

    const int wv = tid >> 6, lane = tid & 63;
    const int row = blockIdx.x * 4 + wv;
    const float4* xr = (const float4*)(X + (size_t)row * DD);
    float4 a = xr[2 * lane], b = xr[2 * lane + 1];
    float s = a.x * a.x + a.y * a.y + a.z * a.z + a.w * a.w
            + b.x * b.x + b.y * b.y + b.z * b.z + b.w * b.w;
#pragma unroll
    for (int off = 32; off; off >>= 1) s += __shfl_down(s, off, 64);

    ushort4 pa = {f2bf(a.x), f2bf(a.y), f2bf(a.z), f2bf(a.w)};
    ushort4 pb = {f2bf(b.x), f2bf(b.y), f2bf(b.z), f2bf(b.w)};
    const int r16 = row >> 4, m = row & 15;
    const int kb = lane >> 2, q = lane & 3;
    ushort4* dst = (ushort4*)((unsigned short*)(ws + WS_XF)
                              + ((size_t)(r16 * 16 + kb) * 64 + q * 16 + m) * 8);
    dst[0] = pa;
    dst[1] = pb;

    __syncthreads();
    const int myc = tg[row];
    int cnt = 0;
    for (int j = lane; j < row; j += 64) cnt += (tg[j] == myc) ? 1 : 0;
#pragma unroll
    for (int off = 32; off; off >>= 1) cnt += __shfl_down(cnt, off, 64);
    if (lane == 0) {
        ws[WS_SQ + row] = s;
        ws[WS_NS + row] = 0.0f;
        ((int*)(ws + WS_RK))[row] = cnt;
        if (cnt < MAXM) ((int*)(ws + WS_MEM))[myc * MAXM + cnt] = row;
    }
    if (blockIdx.x == 0 && tid == 0) {
        ws[WS_LOSS] = 0.0f;
        ((unsigned*)ws)[WS_CTR] = 0u;
        ws[WS_LENP] = 0.0f;
    }
}

// Stage 8 fragments (8 KB) of one K=64 chunk into LDS via global_load_lds.
// gpanel = Xf + panel_r16_base*8192 (shorts). Fragment fi: r16l=fi>>1, kbl=fi&1.
__device__ __forceinline__ void stage8(const unsigned short* __restrict__ gpanel,
                                       int t, int fbase, int lane,
                                       unsigned short* lbase) {
#pragma unroll
    for (int s = 0; s < 8; ++s) {
        const int fi = fbase + s;
        const unsigned short* gp =
            gpanel + ((size_t)((fi >> 1) * 16 + t * 2 + (fi & 1))) * 512 + lane * 8;
        __builtin_amdgcn_global_load_lds(
            (const __attribute__((address_space(1))) int*)gp,
            (__attribute__((address_space(3))) int*)(lbase + fi * 512),
            16, 0, 0);
    }
}

// Gram via bf16 MFMA. 128x128 tile per block (triangular grid, 528 blocks),
// LDS-staged panels: K=64 double-buffered chunks, global_load_lds width-16,
// minimal 2-phase schedule (stage t+1, compute t, one barrier per chunk).
// Global traffic: 256 KB/block -> 135 MB total (was 532 MB with 64x64 no-LDS).
__global__ __launch_bounds__(256, 2) void negsum_kernel(const int* __restrict__ tgt,
                                                        float* __restrict__ ws) {
    __shared__ unsigned short lds[2][2][16][512];   // [buf][A/B][frag][512] = 64 KB
    const int bidx = blockIdx.x;
    int bj = (int)((sqrtf(8.0f * (float)bidx + 1.0f) - 1.0f) * 0.5f);
    while (bj * (bj + 1) / 2 > bidx) --bj;
    while ((bj + 1) * (bj + 2) / 2 <= bidx) ++bj;
    const int bi = bidx - bj * (bj + 1) / 2;   // bi <= bj
    const int i0 = bi * 128, j0 = bj * 128;

    const int tid = threadIdx.x;
    const int w = tid >> 6, lane = tid & 63;
    const int m_ = lane & 15, q = lane >> 4;
    const int wr = (w & 1) * 64, wc = (w >> 1) * 64;   // wave's 64x64 quadrant
    const unsigned short* Xf = (const unsigned short*)(ws + WS_XF);

    // staging roles: waves 0,1 stage A frags 0-7/8-15; waves 2,3 same for B
    const int ab = w >> 1;
    const int fbase = (w & 1) * 8;
    const unsigned short* gpanel = Xf + (size_t)(ab ? bj : bi) * 8 * 8192;
    unsigned short* lb0 = &lds[0][ab][0][0];
    unsigned short* lb1 = &lds[1][ab][0][0];

    f32x4 acc[4][4] = {};

    stage8(gpanel, 0, fbase, lane, lb0);
    __syncthreads();   // drains vmcnt(0): buf0 ready
#pragma unroll 2
    for (int t = 0; t < 8; ++t) {
        const int cur = t & 1;
        if (t < 7) stage8(gpanel, t + 1, fbase, lane, cur ? lb0 : lb1);
#pragma unroll
        for (int kbl = 0; kbl < 2; ++kbl) {
            bf16x8 af[4], bf[4];
#pragma unroll
            for (int u = 0; u < 4; ++u)
                af[u] = *(const bf16x8*)&lds[cur][0][((w & 1) * 4 + u) * 2 + kbl][lane * 8];
#pragma unroll
            for (int v = 0; v < 4; ++v)
                bf[v] = *(const bf16x8*)&lds[cur][1][((w >> 1) * 4 + v) * 2 + kbl][lane * 8];
#pragma unroll
            for (int u = 0; u < 4; ++u)
#pragma unroll
                for (int v = 0; v < 4; ++v)
                    acc[u][v] = __builtin_amdgcn_mfma_f32_16x16x32_bf16(
                        af[u], bf[v], acc[u][v], 0, 0, 0);
        }
        __syncthreads();   // drains stage(t+1) loads + frees buf[cur] for reuse
    }

    // epilogue: C/D map col=lane&15, row=(lane>>4)*4+reg
    const float* sq = ws + WS_SQ;
    float* ns = ws + WS_NS;
    const int* rk = (const int*)(ws + WS_RK);
    float* posd = ws + WS_PD;
    float sjv[4]; int tjv[4], jv[4];
#pragma unroll
    for (int v = 0; v < 4; ++v) {
        int j = j0 + wc + v * 16 + m_;
        jv[v] = j;
        sjv[v] = sq[j];
        tjv[v] = tgt[j];
    }
    float colp[4] = {0.0f, 0.0f, 0.0f, 0.0f};
#pragma unroll
    for (int u = 0; u < 4; ++u) {
#pragma unroll
        for (int r = 0; r < 4; ++r) {
            const int i = i0 + wr + u * 16 + q * 4 + r;
            const float si = sq[i];
            const int ti = tgt[i];
            float rp = 0.0f;
#pragma unroll
            for (int v = 0; v < 4; ++v) {
                float d2 = si + sjv[v] - 2.0f * acc[u][v][r];
                float dist = d2 > 0.0f ? sqrtf(d2) : 0.0f;
                if (tjv[v] != ti) {
                    float e = __expf(MARGINF - dist);
                    rp += e;
                    colp[v] += e;
                } else if (i < jv[v]) {
                    int ra = rk[i], rb = rk[jv[v]];
                    if (ra < MAXM && rb < MAXM) {
                        int hi = ra > rb ? ra : rb;
                        int lo = ra > rb ? rb : ra;
                        posd[ti * TRI + hi * (hi - 1) / 2 + lo] = dist;
                    }
                }
            }
            rp += __shfl_xor(rp, 1, 64);
            rp += __shfl_xor(rp, 2, 64);
            rp += __shfl_xor(rp, 4, 64);
            rp += __shfl_xor(rp, 8, 64);
            if (m_ == 0) atomicAdd(&ns[i], rp);
        }
    }
    if (bi != bj) {   // symmetric contribution: G[j][i] == G[i][j]
#pragma unroll
        for (int v = 0; v < 4; ++v) {
            float cp = colp[v];
            cp += __shfl_xor(cp, 16, 64);
            cp += __shfl_xor(cp, 32, 64);
            if (q == 0) atomicAdd(&ns[jv[v]], cp);
        }
    }
}

// Positive pairs from stored distances; NSLICE blocks per class for occupancy;
// last block finalizes out = loss / len_p.
__global__ __launch_bounds__(256) void pair2_kernel(const int* __restrict__ tgt,
                                                    float* __restrict__ ws,
                                                    float* __restrict__ out) {
    __shared__ float wsum[4];
    __shared__ int csum[4];
    __shared__ bool last;
    const int c = blockIdx.x >> 2;
    const int sl = blockIdx.x & 3;
    const int tid = threadIdx.x;
    const int wv = tid >> 6, lane = tid & 63;

    int ccount = 0;
    for (int j = tid; j < NN; j += 256) ccount += (tgt[j] == c) ? 1 : 0;
#pragma unroll
    for (int off = 32; off; off >>= 1) ccount += __shfl_down(ccount, off, 64);
    if (lane == 0) csum[wv] = ccount;
    __syncthreads();
    int mc = csum[0] + csum[1] + csum[2] + csum[3];
    if (mc > MAXM) mc = MAXM;
    const int P = mc * (mc - 1) / 2;

    const int* mem = (const int*)(ws + WS_MEM) + c * MAXM;
    const float* pd = ws + WS_PD + c * TRI;
    const float* ns = ws + WS_NS;
    float lsum = 0.0f;
    for (int p = tid + sl * 256; p < P; p += 256 * NSLICE) {
        int b = (int)((1.0f + sqrtf(1.0f + 8.0f * (float)p)) * 0.5f);
        while (b * (b - 1) / 2 > p) --b;
        while ((b + 1) * b / 2 <= p) ++b;
        const int a = p - b * (b - 1) / 2;
        const float dist = pd[b * (b - 1) / 2 + a];
        const int i = mem[a], j = mem[b];
        float J = __logf(ns[i] + ns[j]) + dist;
        float h = fmaxf(J, 0.0f);
        lsum += h * h;
    }
#pragma unroll
    for (int off = 32; off; off >>= 1) lsum += __shfl_xor(lsum, off, 64);
    if (lane == 0) wsum[wv] = lsum;
    __syncthreads();
    if (tid == 0) {
        float s = wsum[0] + wsum[1] + wsum[2] + wsum[3];
        if (s != 0.0f) atomicAdd(&ws[WS_LOSS], s);
        if (sl == 0) atomicAdd(&ws[WS_LENP], (float)(mc * (mc - 1)));
        __threadfence();
        unsigned d = atomicAdd((unsigned*)ws + WS_CTR, 1u);
        last = (d == NCLS * NSLICE - 1);
    }
    __syncthreads();
    if (last && tid == 0) {
        float total = atomicAdd(&ws[WS_LOSS], 0.0f);   // device-scope reads
        float lp = atomicAdd(&ws[WS_LENP], 0.0f);
        out[0] = total / lp;
    }
}

extern "C" void kernel_launch(void* const* d_in, const int* in_sizes, int n_in,
                              void* d_out, int out_size, void* d_ws, size_t ws_size,
                              hipStream_t stream) {
    const float* X  = (const float*)d_in[0];
    const int*  tgt = (const int*)d_in[1];
    float* ws  = (float*)d_ws;
    float* out = (float*)d_out;

    hipLaunchKernelGGL(prep_kernel, dim3(NN / 4), dim3(256), 0, stream, X, tgt, ws);
    hipLaunchKernelGGL(negsum_kernel, dim3(NBLK2), dim3(256), 0, stream, tgt, ws);
    hipLaunchKernelGGL(pair2_kernel, dim3(NCLS * NSLICE), dim3(256), 0, stream, tgt, ws, out);
}

// Round 2
// 122.429 us; speedup vs baseline: 1.1005x; 1.1005x over previous
//
#include <hip/hip_runtime.h>
#include <math.h>

#define NN 4096
#define DD 512
#define MARGINF 1.0f
#define NCLS 64
#define MAXM 160
#define TRI (MAXM * (MAXM - 1) / 2)    // 12720
#define PBLK 32                         // 128-row panels
#define NBLK2 (PBLK * (PBLK + 1) / 2)   // 528 triangular 128x128 tiles
#define NSLICE 4                        // pair2 blocks per class

typedef __attribute__((ext_vector_type(8))) short bf16x8;  // 8 bf16 (4 VGPRs)
typedef __attribute__((ext_vector_type(4))) float f32x4;   // 4 fp32 acc

// ws layout (float indices):
#define WS_SQ   0         // float[4096] ||x_i||^2
#define WS_NS   4096      // float[4096] neg_sum
#define WS_LOSS 8192      // float[1] sum hinge^2
#define WS_CTR  8193      // uint[1] pair2 completion counter
#define WS_LENP 8194      // float[1] sum over classes mc*(mc-1)
#define WS_RK   8320      // int[4096] rank within class (atomic-free)
#define WS_MEM  12416     // int[64*160] class member lists (rank-indexed)
#define WS_XF   32768     // ushort[4096*512] FRAGMENT-MAJOR bf16 X (4 MB)
                          //   frag(r16,kb) = 1KB at short-off (r16*16+kb)*512;
                          //   element lane*8+e  (lane=q*16+m, e=k&7)
#define WS_PD   1081344   // float[64*TRI] positive-pair distances

__device__ __forceinline__ unsigned short f2bf(float f) {
    unsigned u = __float_as_uint(f);
    u += 0x7fffu + ((u >> 16) & 1u);   // round-to-nearest-even
    return (unsigned short)(u >> 16);
}

// Row norms + fragment-major bf16 conversion + ATOMIC-FREE class ranks.
__global__ __launch_bounds__(256) void prep_kernel(const float* __restrict__ X,
                                                   const int* __restrict__ tgt,
                                                   float* __restrict__ ws) {
    __shared__ int tg[NN];   // 16 KB
    const int tid = threadIdx.x;
    for (int j = tid; j < NN; j += 256) tg[j] = tgt[j];

    const int wv = tid >> 6, lane = tid & 63;
    const int row = blockIdx.x * 4 + wv;
    const float4* xr = (const float4*)(X + (size_t)row * DD);
    float4 a = xr[2 * lane], b = xr[2 * lane + 1];
    float s = a.x * a.x + a.y * a.y + a.z * a.z + a.w * a.w
            + b.x * b.x + b.y * b.y + b.z * b.z + b.w * b.w;
#pragma unroll
    for (int off = 32; off; off >>= 1) s += __shfl_down(s, off, 64);

    ushort4 pa = {f2bf(a.x), f2bf(a.y), f2bf(a.z), f2bf(a.w)};
    ushort4 pb = {f2bf(b.x), f2bf(b.y), f2bf(b.z), f2bf(b.w)};
    const int r16 = row >> 4, m = row & 15;
    const int kb = lane >> 2, q = lane & 3;
    ushort4* dst = (ushort4*)((unsigned short*)(ws + WS_XF)
                              + ((size_t)(r16 * 16 + kb) * 64 + q * 16 + m) * 8);
    dst[0] = pa;
    dst[1] = pb;

    __syncthreads();
    const int myc = tg[row];
    int cnt = 0;
    for (int j = lane; j < row; j += 64) cnt += (tg[j] == myc) ? 1 : 0;
#pragma unroll
    for (int off = 32; off; off >>= 1) cnt += __shfl_down(cnt, off, 64);
    if (lane == 0) {
        ws[WS_SQ + row] = s;
        ws[WS_NS + row] = 0.0f;
        ((int*)(ws + WS_RK))[row] = cnt;
        if (cnt < MAXM) ((int*)(ws + WS_MEM))[myc * MAXM + cnt] = row;
    }
    if (blockIdx.x == 0 && tid == 0) {
        ws[WS_LOSS] = 0.0f;
        ((unsigned*)ws)[WS_CTR] = 0u;
        ws[WS_LENP] = 0.0f;
    }
}

// Gram via bf16 MFMA. 128x128 tile per block (528 triangular blocks, XCD-
// swizzled), wave = 64x64 (4x4 frags of 16x16x32), NO LDS / NO barriers:
// register double-buffer ring (8 loads in flight/wave), 8 loads feed 16 MFMA
// per K=32 chunk -> cache traffic 270 MB (vs 532 MB at 32x32/wave).
// launch_bounds(256,3): VGPR<=168 -> 3 blocks/CU -> all 528 blocks resident.
__global__ __launch_bounds__(256, 3) void negsum_kernel(const int* __restrict__ tgt,
                                                        float* __restrict__ ws) {
    // XCD-chunked bijective swizzle: 528 = 8 * 66. Blocks with equal
    // blockIdx%8 (same XCD under round-robin dispatch) get contiguous
    // triangular ids -> shared bj column panels stay hot in that XCD's L2.
    const int bidx = (blockIdx.x & 7) * 66 + (blockIdx.x >> 3);
    int bj = (int)((sqrtf(8.0f * (float)bidx + 1.0f) - 1.0f) * 0.5f);
    while (bj * (bj + 1) / 2 > bidx) --bj;
    while ((bj + 1) * (bj + 2) / 2 <= bidx) ++bj;
    const int bi = bidx - bj * (bj + 1) / 2;   // bi <= bj
    const int i0 = bi * 128, j0 = bj * 128;

    const int tid = threadIdx.x;
    const int w = tid >> 6, lane = tid & 63;
    const int m_ = lane & 15, q = lane >> 4;
    const int wr = (w & 1) * 64, wc = (w >> 1) * 64;   // wave's 64x64 quadrant
    const unsigned short* Xf = (const unsigned short*)(ws + WS_XF);

    const unsigned short* pA = Xf + (size_t)((i0 + wr) >> 4) * 8192 + lane * 8;
    const unsigned short* pB = Xf + (size_t)((j0 + wc) >> 4) * 8192 + lane * 8;

    f32x4 acc[4][4] = {};
    bf16x8 bufA[2][4], bufB[2][4];
#pragma unroll
    for (int u = 0; u < 4; ++u) {
        bufA[0][u] = *(const bf16x8*)(pA + u * 8192);
        bufB[0][u] = *(const bf16x8*)(pB + u * 8192);
    }
#pragma unroll
    for (int t = 0; t < 16; ++t) {
        const int cur = t & 1, nx = cur ^ 1;
        if (t < 15) {
#pragma unroll
            for (int u = 0; u < 4; ++u) {
                bufA[nx][u] = *(const bf16x8*)(pA + u * 8192 + (t + 1) * 512);
                bufB[nx][u] = *(const bf16x8*)(pB + u * 8192 + (t + 1) * 512);
            }
        }
#pragma unroll
        for (int u = 0; u < 4; ++u)
#pragma unroll
            for (int v = 0; v < 4; ++v)
                acc[u][v] = __builtin_amdgcn_mfma_f32_16x16x32_bf16(
                    bufA[cur][u], bufB[cur][v], acc[u][v], 0, 0, 0);
    }

    // epilogue: C/D map col=lane&15, row=(lane>>4)*4+reg
    const float* sq = ws + WS_SQ;
    float* ns = ws + WS_NS;
    const int* rk = (const int*)(ws + WS_RK);
    float* posd = ws + WS_PD;
    float sjv[4]; int tjv[4], jv[4];
#pragma unroll
    for (int v = 0; v < 4; ++v) {
        int j = j0 + wc + v * 16 + m_;
        jv[v] = j;
        sjv[v] = sq[j];
        tjv[v] = tgt[j];
    }
    float colp[4] = {0.0f, 0.0f, 0.0f, 0.0f};
#pragma unroll
    for (int u = 0; u < 4; ++u) {
#pragma unroll
        for (int r = 0; r < 4; ++r) {
            const int i = i0 + wr + u * 16 + q * 4 + r;
            const float si = sq[i];
            const int ti = tgt[i];
            float rp = 0.0f;
#pragma unroll
            for (int v = 0; v < 4; ++v) {
                float d2 = si + sjv[v] - 2.0f * acc[u][v][r];
                float dist = d2 > 0.0f ? sqrtf(d2) : 0.0f;
                if (tjv[v] != ti) {
                    float e = __expf(MARGINF - dist);
                    rp += e;
                    colp[v] += e;
                } else if (i < jv[v]) {
                    int ra = rk[i], rb = rk[jv[v]];
                    if (ra < MAXM && rb < MAXM) {
                        int hi = ra > rb ? ra : rb;
                        int lo = ra > rb ? rb : ra;
                        posd[ti * TRI + hi * (hi - 1) / 2 + lo] = dist;
                    }
                }
            }
            rp += __shfl_xor(rp, 1, 64);
            rp += __shfl_xor(rp, 2, 64);
            rp += __shfl_xor(rp, 4, 64);
            rp += __shfl_xor(rp, 8, 64);
            if (m_ == 0) atomicAdd(&ns[i], rp);
        }
    }
    if (bi != bj) {   // symmetric contribution: G[j][i] == G[i][j]
#pragma unroll
        for (int v = 0; v < 4; ++v) {
            float cp = colp[v];
            cp += __shfl_xor(cp, 16, 64);
            cp += __shfl_xor(cp, 32, 64);
            if (q == 0) atomicAdd(&ns[jv[v]], cp);
        }
    }
}

// Positive pairs from stored distances; NSLICE blocks per class for occupancy;
// last block finalizes out = loss / len_p.
__global__ __launch_bounds__(256) void pair2_kernel(const int* __restrict__ tgt,
                                                    float* __restrict__ ws,
                                                    float* __restrict__ out) {
    __shared__ float wsum[4];
    __shared__ int csum[4];
    __shared__ bool last;
    const int c = blockIdx.x >> 2;
    const int sl = blockIdx.x & 3;
    const int tid = threadIdx.x;
    const int wv = tid >> 6, lane = tid & 63;

    int ccount = 0;
    for (int j = tid; j < NN; j += 256) ccount += (tgt[j] == c) ? 1 : 0;
#pragma unroll
    for (int off = 32; off; off >>= 1) ccount += __shfl_down(ccount, off, 64);
    if (lane == 0) csum[wv] = ccount;
    __syncthreads();
    int mc = csum[0] + csum[1] + csum[2] + csum[3];
    if (mc > MAXM) mc = MAXM;
    const int P = mc * (mc - 1) / 2;

    const int* mem = (const int*)(ws + WS_MEM) + c * MAXM;
    const float* pd = ws + WS_PD + c * TRI;
    const float* ns = ws + WS_NS;
    float lsum = 0.0f;
    for (int p = tid + sl * 256; p < P; p += 256 * NSLICE) {
        int b = (int)((1.0f + sqrtf(1.0f + 8.0f * (float)p)) * 0.5f);
        while (b * (b - 1) / 2 > p) --b;
        while ((b + 1) * b / 2 <= p) ++b;
        const int a = p - b * (b - 1) / 2;
        const float dist = pd[b * (b - 1) / 2 + a];
        const int i = mem[a], j = mem[b];
        float J = __logf(ns[i] + ns[j]) + dist;
        float h = fmaxf(J, 0.0f);
        lsum += h * h;
    }
#pragma unroll
    for (int off = 32; off; off >>= 1) lsum += __shfl_xor(lsum, off, 64);
    if (lane == 0) wsum[wv] = lsum;
    __syncthreads();
    if (tid == 0) {
        float s = wsum[0] + wsum[1] + wsum[2] + wsum[3];
        if (s != 0.0f) atomicAdd(&ws[WS_LOSS], s);
        if (sl == 0) atomicAdd(&ws[WS_LENP], (float)(mc * (mc - 1)));
        __threadfence();
        unsigned d = atomicAdd((unsigned*)ws + WS_CTR, 1u);
        last = (d == NCLS * NSLICE - 1);
    }
    __syncthreads();
    if (last && tid == 0) {
        float total = atomicAdd(&ws[WS_LOSS], 0.0f);   // device-scope reads
        float lp = atomicAdd(&ws[WS_LENP], 0.0f);
        out[0] = total / lp;
    }
}

extern "C" void kernel_launch(void* const* d_in, const int* in_sizes, int n_in,
                              void* d_out, int out_size, void* d_ws, size_t ws_size,
                              hipStream_t stream) {
    const float* X  = (const float*)d_in[0];
    const int*  tgt = (const int*)d_in[1];
    float* ws  = (float*)d_ws;
    float* out = (float*)d_out;

    hipLaunchKernelGGL(prep_kernel, dim3(NN / 4), dim3(256), 0, stream, X, tgt, ws);
    hipLaunchKernelGGL(negsum_kernel, dim3(NBLK2), dim3(256), 0, stream, tgt, ws);
    hipLaunchKernelGGL(pair2_kernel, dim3(NCLS * NSLICE), dim3(256), 0, stream, tgt, ws, out);
}

// Round 3
// 122.075 us; speedup vs baseline: 1.1037x; 1.0029x over previous
//
#include <hip/hip_runtime.h>
#include <math.h>

#define NN 4096
#define DD 512
#define MARGINF 1.0f
#define NCLS 64
#define MAXM 160
#define TRI (MAXM * (MAXM - 1) / 2)    // 12720
#define PBLK 32                         // 128-row panels
#define NBLK2 (PBLK * (PBLK + 1) / 2)   // 528 triangular 128x128 tiles
#define NSLICE 4                        // pair2 blocks per class

typedef __attribute__((ext_vector_type(8))) short bf16x8;  // 8 bf16 (4 VGPRs)
typedef __attribute__((ext_vector_type(4))) float f32x4;   // 4 fp32 acc

// ws layout (float indices):
#define WS_SQ   0         // float[4096] ||x_i||^2
#define WS_NS   4096      // float[4096] neg_sum
#define WS_LOSS 8192      // float[1] sum hinge^2
#define WS_CTR  8193      // uint[1] pair2 completion counter
#define WS_LENP 8194      // float[1] sum over classes mc*(mc-1)
#define WS_RK   8320      // int[4096] rank within class (atomic-free)
#define WS_MEM  12416     // int[64*160] class member lists (rank-indexed)
#define WS_XF   32768     // ushort[4096*512] FRAGMENT-MAJOR bf16 X (4 MB)
                          //   frag(r16,kb) = 1KB at short-off (r16*16+kb)*512;
                          //   element lane*8+e  (lane=q*16+m, e=k&7)
#define WS_PD   1081344   // float[64*TRI] positive-pair distances

__device__ __forceinline__ unsigned short f2bf(float f) {
    unsigned u = __float_as_uint(f);
    u += 0x7fffu + ((u >> 16) & 1u);   // round-to-nearest-even
    return (unsigned short)(u >> 16);
}

// Row norms + fragment-major bf16 conversion + ATOMIC-FREE class ranks.
__global__ __launch_bounds__(256) void prep_kernel(const float* __restrict__ X,
                                                   const int* __restrict__ tgt,
                                                   float* __restrict__ ws) {
    __shared__ int tg[NN];   // 16 KB
    const int tid = threadIdx.x;
    for (int j = tid; j < NN; j += 256) tg[j] = tgt[j];

    const int wv = tid >> 6, lane = tid & 63;
    const int row = blockIdx.x * 4 + wv;
    const float4* xr = (const float4*)(X + (size_t)row * DD);
    float4 a = xr[2 * lane], b = xr[2 * lane + 1];
    float s = a.x * a.x + a.y * a.y + a.z * a.z + a.w * a.w
            + b.x * b.x + b.y * b.y + b.z * b.z + b.w * b.w;
#pragma unroll
    for (int off = 32; off; off >>= 1) s += __shfl_down(s, off, 64);

    ushort4 pa = {f2bf(a.x), f2bf(a.y), f2bf(a.z), f2bf(a.w)};
    ushort4 pb = {f2bf(b.x), f2bf(b.y), f2bf(b.z), f2bf(b.w)};
    const int r16 = row >> 4, m = row & 15;
    const int kb = lane >> 2, q = lane & 3;
    ushort4* dst = (ushort4*)((unsigned short*)(ws + WS_XF)
                              + ((size_t)(r16 * 16 + kb) * 64 + q * 16 + m) * 8);
    dst[0] = pa;
    dst[1] = pb;

    __syncthreads();
    const int myc = tg[row];
    int cnt = 0;
    for (int j = lane; j < row; j += 64) cnt += (tg[j] == myc) ? 1 : 0;
#pragma unroll
    for (int off = 32; off; off >>= 1) cnt += __shfl_down(cnt, off, 64);
    if (lane == 0) {
        ws[WS_SQ + row] = s;
        ws[WS_NS + row] = 0.0f;
        ((int*)(ws + WS_RK))[row] = cnt;
        if (cnt < MAXM) ((int*)(ws + WS_MEM))[myc * MAXM + cnt] = row;
    }
    if (blockIdx.x == 0 && tid == 0) {
        ws[WS_LOSS] = 0.0f;
        ((unsigned*)ws)[WS_CTR] = 0u;
        ws[WS_LENP] = 0.0f;
    }
}

// Gram via bf16 MFMA. 128x128 tile per block (528 triangular blocks, XCD-
// swizzled), wave = 64x64 (4x4 frags of 16x16x32), NO LDS / NO barriers.
// DEPTH-2 register ring (3 buffers): loads for chunk t+2 issue at chunk t ->
// 16 outstanding 1KB loads/wave (Little's law: round-2's depth-1 ring halved
// outstanding bytes and halved achieved cache BW). Traffic 270 MB (L2-
// resident per XCD after swizzle). launch_bounds(256,2): 2 blocks/CU covers
// the 2.06 blocks/CU grid.
__global__ __launch_bounds__(256, 2) void negsum_kernel(const int* __restrict__ tgt,
                                                        float* __restrict__ ws) {
    // XCD-chunked bijective swizzle: 528 = 8 * 66. Blocks with equal
    // blockIdx%8 (same XCD under round-robin dispatch) get contiguous
    // triangular ids -> shared panels stay hot in that XCD's L2.
    const int bidx = (blockIdx.x & 7) * 66 + (blockIdx.x >> 3);
    int bj = (int)((sqrtf(8.0f * (float)bidx + 1.0f) - 1.0f) * 0.5f);
    while (bj * (bj + 1) / 2 > bidx) --bj;
    while ((bj + 1) * (bj + 2) / 2 <= bidx) ++bj;
    const int bi = bidx - bj * (bj + 1) / 2;   // bi <= bj
    const int i0 = bi * 128, j0 = bj * 128;

    const int tid = threadIdx.x;
    const int w = tid >> 6, lane = tid & 63;
    const int m_ = lane & 15, q = lane >> 4;
    const int wr = (w & 1) * 64, wc = (w >> 1) * 64;   // wave's 64x64 quadrant
    const unsigned short* Xf = (const unsigned short*)(ws + WS_XF);

    const unsigned short* pA = Xf + (size_t)((i0 + wr) >> 4) * 8192 + lane * 8;
    const unsigned short* pB = Xf + (size_t)((j0 + wc) >> 4) * 8192 + lane * 8;

    f32x4 acc[4][4] = {};
    bf16x8 bufA[3][4], bufB[3][4];
#pragma unroll
    for (int p = 0; p < 2; ++p)
#pragma unroll
        for (int u = 0; u < 4; ++u) {
            bufA[p][u] = *(const bf16x8*)(pA + u * 8192 + p * 512);
            bufB[p][u] = *(const bf16x8*)(pB + u * 8192 + p * 512);
        }
#pragma unroll
    for (int t = 0; t < 16; ++t) {
        const int cur = t % 3, nx = (t + 2) % 3;
        if (t < 14) {
#pragma unroll
            for (int u = 0; u < 4; ++u) {
                bufA[nx][u] = *(const bf16x8*)(pA + u * 8192 + (t + 2) * 512);
                bufB[nx][u] = *(const bf16x8*)(pB + u * 8192 + (t + 2) * 512);
            }
        }
#pragma unroll
        for (int u = 0; u < 4; ++u)
#pragma unroll
            for (int v = 0; v < 4; ++v)
                acc[u][v] = __builtin_amdgcn_mfma_f32_16x16x32_bf16(
                    bufA[cur][u], bufB[cur][v], acc[u][v], 0, 0, 0);
    }

    // epilogue: C/D map col=lane&15, row=(lane>>4)*4+reg
    const float* sq = ws + WS_SQ;
    float* ns = ws + WS_NS;
    const int* rk = (const int*)(ws + WS_RK);
    float* posd = ws + WS_PD;
    float sjv[4]; int tjv[4], jv[4];
#pragma unroll
    for (int v = 0; v < 4; ++v) {
        int j = j0 + wc + v * 16 + m_;
        jv[v] = j;
        sjv[v] = sq[j];
        tjv[v] = tgt[j];
    }
    float colp[4] = {0.0f, 0.0f, 0.0f, 0.0f};
#pragma unroll
    for (int u = 0; u < 4; ++u) {
#pragma unroll
        for (int r = 0; r < 4; ++r) {
            const int i = i0 + wr + u * 16 + q * 4 + r;
            const float si = sq[i];
            const int ti = tgt[i];
            float rp = 0.0f;
#pragma unroll
            for (int v = 0; v < 4; ++v) {
                float d2 = si + sjv[v] - 2.0f * acc[u][v][r];
                float dist = d2 > 0.0f ? sqrtf(d2) : 0.0f;
                if (tjv[v] != ti) {
                    float e = __expf(MARGINF - dist);
                    rp += e;
                    colp[v] += e;
                } else if (i < jv[v]) {
                    int ra = rk[i], rb = rk[jv[v]];
                    if (ra < MAXM && rb < MAXM) {
                        int hi = ra > rb ? ra : rb;
                        int lo = ra > rb ? rb : ra;
                        posd[ti * TRI + hi * (hi - 1) / 2 + lo] = dist;
                    }
                }
            }
            rp += __shfl_xor(rp, 1, 64);
            rp += __shfl_xor(rp, 2, 64);
            rp += __shfl_xor(rp, 4, 64);
            rp += __shfl_xor(rp, 8, 64);
            if (m_ == 0) atomicAdd(&ns[i], rp);
        }
    }
    if (bi != bj) {   // symmetric contribution: G[j][i] == G[i][j]
#pragma unroll
        for (int v = 0; v < 4; ++v) {
            float cp = colp[v];
            cp += __shfl_xor(cp, 16, 64);
            cp += __shfl_xor(cp, 32, 64);
            if (q == 0) atomicAdd(&ns[jv[v]], cp);
        }
    }
}

// Positive pairs from stored distances; NSLICE blocks per class for occupancy;
// last block finalizes out = loss / len_p.
__global__ __launch_bounds__(256) void pair2_kernel(const int* __restrict__ tgt,
                                                    float* __restrict__ ws,
                                                    float* __restrict__ out) {
    __shared__ float wsum[4];
    __shared__ int csum[4];
    __shared__ bool last;
    const int c = blockIdx.x >> 2;
    const int sl = blockIdx.x & 3;
    const int tid = threadIdx.x;
    const int wv = tid >> 6, lane = tid & 63;

    int ccount = 0;
    for (int j = tid; j < NN; j += 256) ccount += (tgt[j] == c) ? 1 : 0;
#pragma unroll
    for (int off = 32; off; off >>= 1) ccount += __shfl_down(ccount, off, 64);
    if (lane == 0) csum[wv] = ccount;
    __syncthreads();
    int mc = csum[0] + csum[1] + csum[2] + csum[3];
    if (mc > MAXM) mc = MAXM;
    const int P = mc * (mc - 1) / 2;

    const int* mem = (const int*)(ws + WS_MEM) + c * MAXM;
    const float* pd = ws + WS_PD + c * TRI;
    const float* ns = ws + WS_NS;
    float lsum = 0.0f;
    for (int p = tid + sl * 256; p < P; p += 256 * NSLICE) {
        int b = (int)((1.0f + sqrtf(1.0f + 8.0f * (float)p)) * 0.5f);
        while (b * (b - 1) / 2 > p) --b;
        while ((b + 1) * b / 2 <= p) ++b;
        const int a = p - b * (b - 1) / 2;
        const float dist = pd[b * (b - 1) / 2 + a];
        const int i = mem[a], j = mem[b];
        float J = __logf(ns[i] + ns[j]) + dist;
        float h = fmaxf(J, 0.0f);
        lsum += h * h;
    }
#pragma unroll
    for (int off = 32; off; off >>= 1) lsum += __shfl_xor(lsum, off, 64);
    if (lane == 0) wsum[wv] = lsum;
    __syncthreads();
    if (tid == 0) {
        float s = wsum[0] + wsum[1] + wsum[2] + wsum[3];
        if (s != 0.0f) atomicAdd(&ws[WS_LOSS], s);
        if (sl == 0) atomicAdd(&ws[WS_LENP], (float)(mc * (mc - 1)));
        __threadfence();
        unsigned d = atomicAdd((unsigned*)ws + WS_CTR, 1u);
        last = (d == NCLS * NSLICE - 1);
    }
    __syncthreads();
    if (last && tid == 0) {
        float total = atomicAdd(&ws[WS_LOSS], 0.0f);   // device-scope reads
        float lp = atomicAdd(&ws[WS_LENP], 0.0f);
        out[0] = total / lp;
    }
}

extern "C" void kernel_launch(void* const* d_in, const int* in_sizes, int n_in,
                              void* d_out, int out_size, void* d_ws, size_t ws_size,
                              hipStream_t stream) {
    const float* X  = (const float*)d_in[0];
    const int*  tgt = (const int*)d_in[1];
    float* ws  = (float*)d_ws;
    float* out = (float*)d_out;

    hipLaunchKernelGGL(prep_kernel, dim3(NN / 4), dim3(256), 0, stream, X, tgt, ws);
    hipLaunchKernelGGL(negsum_kernel, dim3(NBLK2), dim3(256), 0, stream, tgt, ws);
    hipLaunchKernelGGL(pair2_kernel, dim3(NCLS * NSLICE), dim3(256), 0, stream, tgt, ws, out);
}

// Round 4
// 115.664 us; speedup vs baseline: 1.1649x; 1.0554x over previous
//
#include <hip/hip_runtime.h>
#include <math.h>

#define NN 4096
#define DD 512
#define MARGINF 1.0f
#define NCLS 64
#define MAXM 160
#define TRI (MAXM * (MAXM - 1) / 2)   // 12720
#define NBLK 2080                     // 64*65/2 triangular 64-tiles
#define NSLICE 4                      // pair2 blocks per class

typedef __attribute__((ext_vector_type(8))) short bf16x8;  // 8 bf16 (4 VGPRs)
typedef __attribute__((ext_vector_type(4))) float f32x4;   // 4 fp32 acc

// ws layout (float indices):
#define WS_SQ   0         // float[4096] ||x_i||^2
#define WS_NS   4096      // float[4096] neg_sum
#define WS_LOSS 8192      // float[1] sum hinge^2
#define WS_CTR  8193      // uint[1] pair2 completion counter
#define WS_LENP 8194      // float[1] sum over classes mc*(mc-1)
#define WS_RK   8320      // int[4096] rank within class (atomic-free)
#define WS_MEM  12416     // int[64*160] class member lists (rank-indexed)
#define WS_XF   32768     // ushort[4096*512] FRAGMENT-MAJOR bf16 X (4 MB)
                          //   frag(r16,kb) = 1KB at short-off (r16*16+kb)*512;
                          //   element lane*8+e  (lane=q*16+m, e=k&7)
#define WS_PD   1081344   // float[64*TRI] positive-pair distances

__device__ __forceinline__ unsigned short f2bf(float f) {
    unsigned u = __float_as_uint(f);
    u += 0x7fffu + ((u >> 16) & 1u);   // round-to-nearest-even
    return (unsigned short)(u >> 16);
}

// Row norms + fragment-major bf16 conversion + ATOMIC-FREE class ranks.
__global__ __launch_bounds__(256) void prep_kernel(const float* __restrict__ X,
                                                   const int* __restrict__ tgt,
                                                   float* __restrict__ ws) {
    __shared__ int tg[NN];   // 16 KB
    const int tid = threadIdx.x;
    for (int j = tid; j < NN; j += 256) tg[j] = tgt[j];

    const int wv = tid >> 6, lane = tid & 63;
    const int row = blockIdx.x * 4 + wv;
    const float4* xr = (const float4*)(X + (size_t)row * DD);
    float4 a = xr[2 * lane], b = xr[2 * lane + 1];
    float s = a.x * a.x + a.y * a.y + a.z * a.z + a.w * a.w
            + b.x * b.x + b.y * b.y + b.z * b.z + b.w * b.w;
#pragma unroll
    for (int off = 32; off; off >>= 1) s += __shfl_down(s, off, 64);

    ushort4 pa = {f2bf(a.x), f2bf(a.y), f2bf(a.z), f2bf(a.w)};
    ushort4 pb = {f2bf(b.x), f2bf(b.y), f2bf(b.z), f2bf(b.w)};
    const int r16 = row >> 4, m = row & 15;
    const int kb = lane >> 2, q = lane & 3;
    ushort4* dst = (ushort4*)((unsigned short*)(ws + WS_XF)
                              + ((size_t)(r16 * 16 + kb) * 64 + q * 16 + m) * 8);
    dst[0] = pa;
    dst[1] = pb;

    __syncthreads();
    const int myc = tg[row];
    int cnt = 0;
    for (int j = lane; j < row; j += 64) cnt += (tg[j] == myc) ? 1 : 0;
#pragma unroll
    for (int off = 32; off; off >>= 1) cnt += __shfl_down(cnt, off, 64);
    if (lane == 0) {
        ws[WS_SQ + row] = s;
        ws[WS_NS + row] = 0.0f;
        ((int*)(ws + WS_RK))[row] = cnt;
        if (cnt < MAXM) ((int*)(ws + WS_MEM))[myc * MAXM + cnt] = row;
    }
    if (blockIdx.x == 0 && tid == 0) {
        ws[WS_LOSS] = 0.0f;
        ((unsigned*)ws)[WS_CTR] = 0u;
        ws[WS_LENP] = 0.0f;
    }
}

// Gram via bf16 MFMA. 64x64 tile per block (2080 triangular blocks, XCD-
// swizzled 2080=8*260), wave = 32x32 (2x2 frags), NO LDS / NO barriers.
// OCCUPANCY PLAY: rounds 0/2/3 showed achieved cache BW = resident-waves x
// ~0.67 TB/s-chip/wave regardless of prefetch depth (compiler rescheds rings
// away). So: minimal register state (depth-1 double buffer, 8 bf16x8 = 32
// VGPR + 16 acc) + launch_bounds(256,8) -> <=64 VGPR -> 8 waves/SIMD ->
// 32 waves/CU, 4x round-2's occupancy. 532 MB @ ~21 TB/s -> ~25 us.
__global__ __launch_bounds__(256, 8) void negsum_kernel(const int* __restrict__ tgt,
                                                        float* __restrict__ ws) {
    // XCD-chunked bijective swizzle: blocks with equal blockIdx%8 (same XCD
    // under round-robin dispatch) get 260 contiguous triangular ids.
    const int bidx = (blockIdx.x & 7) * 260 + (blockIdx.x >> 3);
    int bj = (int)((sqrtf(8.0f * (float)bidx + 1.0f) - 1.0f) * 0.5f);
    while (bj * (bj + 1) / 2 > bidx) --bj;
    while ((bj + 1) * (bj + 2) / 2 <= bidx) ++bj;
    const int bi = bidx - bj * (bj + 1) / 2;   // bi <= bj
    const int i0 = bi * 64, j0 = bj * 64;

    const int tid = threadIdx.x;
    const int w = tid >> 6, lane = tid & 63;
    const int m_ = lane & 15, q = lane >> 4;
    const int wr = (w & 1) * 32, wc = (w >> 1) * 32;   // wave's 32x32 quadrant
    const unsigned short* Xf = (const unsigned short*)(ws + WS_XF);

    const unsigned short* pA = Xf + (size_t)((i0 + wr) >> 4) * 8192 + lane * 8;
    const unsigned short* pB = Xf + (size_t)((j0 + wc) >> 4) * 8192 + lane * 8;

    f32x4 acc[2][2] = {};
    bf16x8 bufA[2][2], bufB[2][2];
#pragma unroll
    for (int u = 0; u < 2; ++u) {
        bufA[0][u] = *(const bf16x8*)(pA + u * 8192);
        bufB[0][u] = *(const bf16x8*)(pB + u * 8192);
    }
#pragma unroll
    for (int t = 0; t < 16; ++t) {
        const int cur = t & 1, nx = cur ^ 1;
        if (t < 15) {
#pragma unroll
            for (int u = 0; u < 2; ++u) {
                bufA[nx][u] = *(const bf16x8*)(pA + u * 8192 + (t + 1) * 512);
                bufB[nx][u] = *(const bf16x8*)(pB + u * 8192 + (t + 1) * 512);
            }
        }
        acc[0][0] = __builtin_amdgcn_mfma_f32_16x16x32_bf16(bufA[cur][0], bufB[cur][0], acc[0][0], 0, 0, 0);
        acc[0][1] = __builtin_amdgcn_mfma_f32_16x16x32_bf16(bufA[cur][0], bufB[cur][1], acc[0][1], 0, 0, 0);
        acc[1][0] = __builtin_amdgcn_mfma_f32_16x16x32_bf16(bufA[cur][1], bufB[cur][0], acc[1][0], 0, 0, 0);
        acc[1][1] = __builtin_amdgcn_mfma_f32_16x16x32_bf16(bufA[cur][1], bufB[cur][1], acc[1][1], 0, 0, 0);
    }

    // epilogue: C/D map col=lane&15, row=(lane>>4)*4+reg
    const float* sq = ws + WS_SQ;
    float* ns = ws + WS_NS;
    const int* rk = (const int*)(ws + WS_RK);
    float* posd = ws + WS_PD;
    float sjv[2]; int tjv[2], jv[2];
#pragma unroll
    for (int v = 0; v < 2; ++v) {
        int j = j0 + wc + v * 16 + m_;
        jv[v] = j;
        sjv[v] = sq[j];
        tjv[v] = tgt[j];
    }
    float colp[2] = {0.0f, 0.0f};
#pragma unroll
    for (int u = 0; u < 2; ++u) {
#pragma unroll
        for (int r = 0; r < 4; ++r) {
            const int i = i0 + wr + u * 16 + q * 4 + r;
            const float si = sq[i];
            const int ti = tgt[i];
            float rp = 0.0f;
#pragma unroll
            for (int v = 0; v < 2; ++v) {
                float d2 = si + sjv[v] - 2.0f * acc[u][v][r];
                float dist = d2 > 0.0f ? sqrtf(d2) : 0.0f;
                if (tjv[v] != ti) {
                    float e = __expf(MARGINF - dist);
                    rp += e;
                    colp[v] += e;
                } else if (i < jv[v]) {
                    int ra = rk[i], rb = rk[jv[v]];
                    if (ra < MAXM && rb < MAXM) {
                        int hi = ra > rb ? ra : rb;
                        int lo = ra > rb ? rb : ra;
                        posd[ti * TRI + hi * (hi - 1) / 2 + lo] = dist;
                    }
                }
            }
            rp += __shfl_xor(rp, 1, 64);
            rp += __shfl_xor(rp, 2, 64);
            rp += __shfl_xor(rp, 4, 64);
            rp += __shfl_xor(rp, 8, 64);
            if (m_ == 0) atomicAdd(&ns[i], rp);
        }
    }
    if (bi != bj) {   // symmetric contribution: G[j][i] == G[i][j]
#pragma unroll
        for (int v = 0; v < 2; ++v) {
            float cp = colp[v];
            cp += __shfl_xor(cp, 16, 64);
            cp += __shfl_xor(cp, 32, 64);
            if (q == 0) atomicAdd(&ns[jv[v]], cp);
        }
    }
}

// Positive pairs from stored distances; NSLICE blocks per class for occupancy;
// last block finalizes out = loss / len_p.
__global__ __launch_bounds__(256) void pair2_kernel(const int* __restrict__ tgt,
                                                    float* __restrict__ ws,
                                                    float* __restrict__ out) {
    __shared__ float wsum[4];
    __shared__ int csum[4];
    __shared__ bool last;
    const int c = blockIdx.x >> 2;
    const int sl = blockIdx.x & 3;
    const int tid = threadIdx.x;
    const int wv = tid >> 6, lane = tid & 63;

    int ccount = 0;
    for (int j = tid; j < NN; j += 256) ccount += (tgt[j] == c) ? 1 : 0;
#pragma unroll
    for (int off = 32; off; off >>= 1) ccount += __shfl_down(ccount, off, 64);
    if (lane == 0) csum[wv] = ccount;
    __syncthreads();
    int mc = csum[0] + csum[1] + csum[2] + csum[3];
    if (mc > MAXM) mc = MAXM;
    const int P = mc * (mc - 1) / 2;

    const int* mem = (const int*)(ws + WS_MEM) + c * MAXM;
    const float* pd = ws + WS_PD + c * TRI;
    const float* ns = ws + WS_NS;
    float lsum = 0.0f;
    for (int p = tid + sl * 256; p < P; p += 256 * NSLICE) {
        int b = (int)((1.0f + sqrtf(1.0f + 8.0f * (float)p)) * 0.5f);
        while (b * (b - 1) / 2 > p) --b;
        while ((b + 1) * b / 2 <= p) ++b;
        const int a = p - b * (b - 1) / 2;
        const float dist = pd[b * (b - 1) / 2 + a];
        const int i = mem[a], j = mem[b];
        float J = __logf(ns[i] + ns[j]) + dist;
        float h = fmaxf(J, 0.0f);
        lsum += h * h;
    }
#pragma unroll
    for (int off = 32; off; off >>= 1) lsum += __shfl_xor(lsum, off, 64);
    if (lane == 0) wsum[wv] = lsum;
    __syncthreads();
    if (tid == 0) {
        float s = wsum[0] + wsum[1] + wsum[2] + wsum[3];
        if (s != 0.0f) atomicAdd(&ws[WS_LOSS], s);
        if (sl == 0) atomicAdd(&ws[WS_LENP], (float)(mc * (mc - 1)));
        __threadfence();
        unsigned d = atomicAdd((unsigned*)ws + WS_CTR, 1u);
        last = (d == NCLS * NSLICE - 1);
    }
    __syncthreads();
    if (last && tid == 0) {
        float total = atomicAdd(&ws[WS_LOSS], 0.0f);   // device-scope reads
        float lp = atomicAdd(&ws[WS_LENP], 0.0f);
        out[0] = total / lp;
    }
}

extern "C" void kernel_launch(void* const* d_in, const int* in_sizes, int n_in,
                              void* d_out, int out_size, void* d_ws, size_t ws_size,
                              hipStream_t stream) {
    const float* X  = (const float*)d_in[0];
    const int*  tgt = (const int*)d_in[1];
    float* ws  = (float*)d_ws;
    float* out = (float*)d_out;

    hipLaunchKernelGGL(prep_kernel, dim3(NN / 4), dim3(256), 0, stream, X, tgt, ws);
    hipLaunchKernelGGL(negsum_kernel, dim3(NBLK), dim3(256), 0, stream, tgt, ws);
    hipLaunchKernelGGL(pair2_kernel, dim3(NCLS * NSLICE), dim3(256), 0, stream, tgt, ws, out);
}

// Round 5
// 110.730 us; speedup vs baseline: 1.2168x; 1.0446x over previous
//
#include <hip/hip_runtime.h>
#include <math.h>

#define NN 4096
#define DD 512
#define MARGINF 1.0f
#define NCLS 64
#define MAXM 160
#define TRI (MAXM * (MAXM - 1) / 2)   // 12720
#define NBLK 2080                     // 64*65/2 triangular 64-tiles
#define NSLICE 4                      // pair2 blocks per class

typedef __attribute__((ext_vector_type(8))) short bf16x8;  // 8 bf16 (4 VGPRs)
typedef __attribute__((ext_vector_type(4))) float f32x4;   // 4 fp32 acc

// ws layout (float indices):
#define WS_SQ   0         // float[4096] ||x_i||^2
#define WS_NS   4096      // float[4096] neg_sum
#define WS_LOSS 8192      // float[1] sum hinge^2
#define WS_CTR  8193      // uint[1] pair2 completion counter
#define WS_LENP 8194      // float[1] sum over classes mc*(mc-1)
#define WS_RK   8320      // int[4096] rank within class (atomic-free)
#define WS_MEM  12416     // int[64*160] class member lists (rank-indexed)
#define WS_XF   32768     // ushort[4096*512] FRAGMENT-MAJOR bf16 X (4 MB)
                          //   frag(r16,kb) = 1KB at short-off (r16*16+kb)*512;
                          //   element lane*8+e  (lane=q*16+m, e=k&7)
#define WS_PD   1081344   // float[64*TRI] positive-pair distances

__device__ __forceinline__ unsigned short f2bf(float f) {
    unsigned u = __float_as_uint(f);
    u += 0x7fffu + ((u >> 16) & 1u);   // round-to-nearest-even
    return (unsigned short)(u >> 16);
}

// Row norms + fragment-major bf16 conversion + ATOMIC-FREE class ranks.
__global__ __launch_bounds__(256) void prep_kernel(const float* __restrict__ X,
                                                   const int* __restrict__ tgt,
                                                   float* __restrict__ ws) {
    __shared__ int tg[NN];   // 16 KB
    const int tid = threadIdx.x;
    for (int j = tid; j < NN; j += 256) tg[j] = tgt[j];

    const int wv = tid >> 6, lane = tid & 63;
    const int row = blockIdx.x * 4 + wv;
    const float4* xr = (const float4*)(X + (size_t)row * DD);
    float4 a = xr[2 * lane], b = xr[2 * lane + 1];
    float s = a.x * a.x + a.y * a.y + a.z * a.z + a.w * a.w
            + b.x * b.x + b.y * b.y + b.z * b.z + b.w * b.w;
#pragma unroll
    for (int off = 32; off; off >>= 1) s += __shfl_down(s, off, 64);

    ushort4 pa = {f2bf(a.x), f2bf(a.y), f2bf(a.z), f2bf(a.w)};
    ushort4 pb = {f2bf(b.x), f2bf(b.y), f2bf(b.z), f2bf(b.w)};
    const int r16 = row >> 4, m = row & 15;
    const int kb = lane >> 2, q = lane & 3;
    ushort4* dst = (ushort4*)((unsigned short*)(ws + WS_XF)
                              + ((size_t)(r16 * 16 + kb) * 64 + q * 16 + m) * 8);
    dst[0] = pa;
    dst[1] = pb;

    __syncthreads();
    const int myc = tg[row];
    int cnt = 0;
    for (int j = lane; j < row; j += 64) cnt += (tg[j] == myc) ? 1 : 0;
#pragma unroll
    for (int off = 32; off; off >>= 1) cnt += __shfl_down(cnt, off, 64);
    if (lane == 0) {
        ws[WS_SQ + row] = s;
        ws[WS_NS + row] = 0.0f;
        ((int*)(ws + WS_RK))[row] = cnt;
        if (cnt < MAXM) ((int*)(ws + WS_MEM))[myc * MAXM + cnt] = row;
    }
    if (blockIdx.x == 0 && tid == 0) {
        ws[WS_LOSS] = 0.0f;
        ((unsigned*)ws)[WS_CTR] = 0u;
        ws[WS_LENP] = 0.0f;
    }
}

// Gram via bf16 MFMA. 64x64 tile per block (2080 triangular blocks, XCD-
// swizzled), wave = 32x32 (2x2 frags). TRAFFIC PLAY: R0 vs R4 proved a
// ~12.7 TB/s cache-datapath ceiling independent of wave count (20 vs 32
// waves/CU, same 532 MB, same 42 us). So: share panels in the block via
// LDS -> fetched bytes halve to 266 MB (one copy per block, 128 KB), LDS
// serves re-reads at 69 TB/s. R1's LDS failure was occupancy (64 KB LDS,
// 2 blk/CU, 2.06-deep grid); here K-chunk=32 -> 16 KB dbuf -> 8 blk/CU,
// 32 waves/CU, 8.1-deep grid: barrier drains fully overlapped.
// Staging: fragment-major layout = 1 KB frags, exactly one wave-level
// global_load_lds (width 16) each; 8 frags/chunk, 2 per wave.
__global__ __launch_bounds__(256, 8) void negsum_kernel(const int* __restrict__ tgt,
                                                        float* __restrict__ ws) {
    __shared__ unsigned short lds[2][8][512];   // [buf][frag: 0-3 A, 4-7 B] 16 KB
    // XCD-chunked bijective swizzle: 2080 = 8 * 260.
    const int bidx = (blockIdx.x & 7) * 260 + (blockIdx.x >> 3);
    int bj = (int)((sqrtf(8.0f * (float)bidx + 1.0f) - 1.0f) * 0.5f);
    while (bj * (bj + 1) / 2 > bidx) --bj;
    while ((bj + 1) * (bj + 2) / 2 <= bidx) ++bj;
    const int bi = bidx - bj * (bj + 1) / 2;   // bi <= bj
    const int i0 = bi * 64, j0 = bj * 64;

    const int tid = threadIdx.x;
    const int w = tid >> 6, lane = tid & 63;
    const int m_ = lane & 15, q = lane >> 4;
    const int wr = (w & 1) * 32, wc = (w >> 1) * 32;   // wave's 32x32 quadrant
    const unsigned short* Xf = (const unsigned short*)(ws + WS_XF);
    const int air0 = i0 >> 4, bjr0 = j0 >> 4;

    // this wave stages frags {2w, 2w+1} of each chunk
    int fr16[2];
#pragma unroll
    for (int s = 0; s < 2; ++s) {
        const int f = w * 2 + s;
        fr16[s] = (f < 4) ? (air0 + f) : (bjr0 + (f - 4));
    }

    f32x4 acc[2][2] = {};

    // prologue: stage chunk 0 into buf 0
#pragma unroll
    for (int s = 0; s < 2; ++s) {
        const unsigned short* gp = Xf + ((size_t)fr16[s] * 16 + 0) * 512 + lane * 8;
        __builtin_amdgcn_global_load_lds(
            (const __attribute__((address_space(1))) int*)gp,
            (__attribute__((address_space(3))) int*)(&lds[0][w * 2 + s][0]),
            16, 0, 0);
    }
    __syncthreads();

#pragma unroll
    for (int t = 0; t < 16; ++t) {
        const int cur = t & 1, nx = cur ^ 1;
        if (t < 15) {
#pragma unroll
            for (int s = 0; s < 2; ++s) {
                const unsigned short* gp =
                    Xf + ((size_t)fr16[s] * 16 + (t + 1)) * 512 + lane * 8;
                __builtin_amdgcn_global_load_lds(
                    (const __attribute__((address_space(1))) int*)gp,
                    (__attribute__((address_space(3))) int*)(&lds[nx][w * 2 + s][0]),
                    16, 0, 0);
            }
        }
        bf16x8 af[2], bf[2];
#pragma unroll
        for (int u = 0; u < 2; ++u)
            af[u] = *(const bf16x8*)&lds[cur][(w & 1) * 2 + u][lane * 8];
#pragma unroll
        for (int v = 0; v < 2; ++v)
            bf[v] = *(const bf16x8*)&lds[cur][4 + (w >> 1) * 2 + v][lane * 8];
        acc[0][0] = __builtin_amdgcn_mfma_f32_16x16x32_bf16(af[0], bf[0], acc[0][0], 0, 0, 0);
        acc[0][1] = __builtin_amdgcn_mfma_f32_16x16x32_bf16(af[0], bf[1], acc[0][1], 0, 0, 0);
        acc[1][0] = __builtin_amdgcn_mfma_f32_16x16x32_bf16(af[1], bf[0], acc[1][0], 0, 0, 0);
        acc[1][1] = __builtin_amdgcn_mfma_f32_16x16x32_bf16(af[1], bf[1], acc[1][1], 0, 0, 0);
        __syncthreads();   // stage(t+1) drained; buf[cur] free for t+1's stage
    }

    // epilogue: C/D map col=lane&15, row=(lane>>4)*4+reg
    const float* sq = ws + WS_SQ;
    float* ns = ws + WS_NS;
    const int* rk = (const int*)(ws + WS_RK);
    float* posd = ws + WS_PD;
    float sjv[2]; int tjv[2], jv[2];
#pragma unroll
    for (int v = 0; v < 2; ++v) {
        int j = j0 + wc + v * 16 + m_;
        jv[v] = j;
        sjv[v] = sq[j];
        tjv[v] = tgt[j];
    }
    float colp[2] = {0.0f, 0.0f};
#pragma unroll
    for (int u = 0; u < 2; ++u) {
#pragma unroll
        for (int r = 0; r < 4; ++r) {
            const int i = i0 + wr + u * 16 + q * 4 + r;
            const float si = sq[i];
            const int ti = tgt[i];
            float rp = 0.0f;
#pragma unroll
            for (int v = 0; v < 2; ++v) {
                float d2 = si + sjv[v] - 2.0f * acc[u][v][r];
                float dist = d2 > 0.0f ? sqrtf(d2) : 0.0f;
                if (tjv[v] != ti) {
                    float e = __expf(MARGINF - dist);
                    rp += e;
                    colp[v] += e;
                } else if (i < jv[v]) {
                    int ra = rk[i], rb = rk[jv[v]];
                    if (ra < MAXM && rb < MAXM) {
                        int hi = ra > rb ? ra : rb;
                        int lo = ra > rb ? rb : ra;
                        posd[ti * TRI + hi * (hi - 1) / 2 + lo] = dist;
                    }
                }
            }
            rp += __shfl_xor(rp, 1, 64);
            rp += __shfl_xor(rp, 2, 64);
            rp += __shfl_xor(rp, 4, 64);
            rp += __shfl_xor(rp, 8, 64);
            if (m_ == 0) atomicAdd(&ns[i], rp);
        }
    }
    if (bi != bj) {   // symmetric contribution: G[j][i] == G[i][j]
#pragma unroll
        for (int v = 0; v < 2; ++v) {
            float cp = colp[v];
            cp += __shfl_xor(cp, 16, 64);
            cp += __shfl_xor(cp, 32, 64);
            if (q == 0) atomicAdd(&ns[jv[v]], cp);
        }
    }
}

// Positive pairs from stored distances; NSLICE blocks per class for occupancy;
// last block finalizes out = loss / len_p.
__global__ __launch_bounds__(256) void pair2_kernel(const int* __restrict__ tgt,
                                                    float* __restrict__ ws,
                                                    float* __restrict__ out) {
    __shared__ float wsum[4];
    __shared__ int csum[4];
    __shared__ bool last;
    const int c = blockIdx.x >> 2;
    const int sl = blockIdx.x & 3;
    const int tid = threadIdx.x;
    const int wv = tid >> 6, lane = tid & 63;

    int ccount = 0;
    for (int j = tid; j < NN; j += 256) ccount += (tgt[j] == c) ? 1 : 0;
#pragma unroll
    for (int off = 32; off; off >>= 1) ccount += __shfl_down(ccount, off, 64);
    if (lane == 0) csum[wv] = ccount;
    __syncthreads();
    int mc = csum[0] + csum[1] + csum[2] + csum[3];
    if (mc > MAXM) mc = MAXM;
    const int P = mc * (mc - 1) / 2;

    const int* mem = (const int*)(ws + WS_MEM) + c * MAXM;
    const float* pd = ws + WS_PD + c * TRI;
    const float* ns = ws + WS_NS;
    float lsum = 0.0f;
    for (int p = tid + sl * 256; p < P; p += 256 * NSLICE) {
        int b = (int)((1.0f + sqrtf(1.0f + 8.0f * (float)p)) * 0.5f);
        while (b * (b - 1) / 2 > p) --b;
        while ((b + 1) * b / 2 <= p) ++b;
        const int a = p - b * (b - 1) / 2;
        const float dist = pd[b * (b - 1) / 2 + a];
        const int i = mem[a], j = mem[b];
        float J = __logf(ns[i] + ns[j]) + dist;
        float h = fmaxf(J, 0.0f);
        lsum += h * h;
    }
#pragma unroll
    for (int off = 32; off; off >>= 1) lsum += __shfl_xor(lsum, off, 64);
    if (lane == 0) wsum[wv] = lsum;
    __syncthreads();
    if (tid == 0) {
        float s = wsum[0] + wsum[1] + wsum[2] + wsum[3];
        if (s != 0.0f) atomicAdd(&ws[WS_LOSS], s);
        if (sl == 0) atomicAdd(&ws[WS_LENP], (float)(mc * (mc - 1)));
        __threadfence();
        unsigned d = atomicAdd((unsigned*)ws + WS_CTR, 1u);
        last = (d == NCLS * NSLICE - 1);
    }
    __syncthreads();
    if (last && tid == 0) {
        float total = atomicAdd(&ws[WS_LOSS], 0.0f);   // device-scope reads
        float lp = atomicAdd(&ws[WS_LENP], 0.0f);
        out[0] = total / lp;
    }
}

extern "C" void kernel_launch(void* const* d_in, const int* in_sizes, int n_in,
                              void* d_out, int out_size, void* d_ws, size_t ws_size,
                              hipStream_t stream) {
    const float* X  = (const float*)d_in[0];
    const int*  tgt = (const int*)d_in[1];
    float* ws  = (float*)d_ws;
    float* out = (float*)d_out;

    hipLaunchKernelGGL(prep_kernel, dim3(NN / 4), dim3(256), 0, stream, X, tgt, ws);
    hipLaunchKernelGGL(negsum_kernel, dim3(NBLK), dim3(256), 0, stream, tgt, ws);
    hipLaunchKernelGGL(pair2_kernel, dim3(NCLS * NSLICE), dim3(256), 0, stream, tgt, ws, out);
}